// Round 9
// baseline (97.130 us; speedup 1.0000x reference)
//
#include <hip/hip_runtime.h>
#include <hip/hip_bf16.h>
#include <math.h>

// ---------------- problem constants ----------------
#define SEQ   4096
#define EMB   1024
#define NH    8
#define HD    128
#define NSLOT 15   // distinct gathered positions: 0..10, S-4..S-1 (+1 zero pad slot = 16)

typedef __attribute__((ext_vector_type(8))) short bf16x8;
typedef __attribute__((ext_vector_type(4))) float f32x4;
typedef __attribute__((ext_vector_type(4))) unsigned short ushort4v;
typedef unsigned short ushort_t;

// per-t slot multiplicity masks, 2 bits per slot (slot s at bits 2s..2s+1).
__device__ __constant__ unsigned int MULT[8] = {
    0x00005555u,  // t=0:   slots {0..7}
    0x10015055u,  // t=1:   {0,1,2,3,6,7,8,14}
    0x14050055u,  // t=2:   {0,1,2,3,8,9,13,14}
    0x15100055u,  // t=3:   {0,1,2,3,10,12,13,14}
    0x15800015u,  // t=S-3: {0,1,2, 11x2, 12,13,14}
    0x16800005u,  // t=S-2: {0,1, 11x2, 12x2, 13,14}
    0x1A800001u,  // t=S-1: {0, 11x2, 12x2, 13x2, 14}
    0x15400055u   // interior: {0,1,2,3,11,12,13,14}
};

__device__ __forceinline__ unsigned short f2bf(float x) {
    unsigned int u = __float_as_uint(x);
    return (unsigned short)((u + 0x7FFFu + ((u >> 16) & 1u)) >> 16);
}

// 8x fp32 -> bf16x8 via v_cvt_pk_bf16_f32 (RNE, 1 inst per pair; no builtin on gfx950)
__device__ __forceinline__ bf16x8 cvt8(float4 a, float4 b) {
    union { unsigned int u[4]; bf16x8 v; } r;
    asm("v_cvt_pk_bf16_f32 %0, %1, %2" : "=v"(r.u[0]) : "v"(a.x), "v"(a.y));
    asm("v_cvt_pk_bf16_f32 %0, %1, %2" : "=v"(r.u[1]) : "v"(a.z), "v"(a.w));
    asm("v_cvt_pk_bf16_f32 %0, %1, %2" : "=v"(r.u[2]) : "v"(b.x), "v"(b.y));
    asm("v_cvt_pk_bf16_f32 %0, %1, %2" : "=v"(r.u[3]) : "v"(b.z), "v"(b.w));
    return r.v;
}

// bijective chunked XCD swizzle (nwg % 8 == 0)
__device__ __forceinline__ int xcd_swz(int bid, int nwg) {
    int cpx = nwg >> 3;
    return (bid & 7) * cpx + (bid >> 3);
}

// ---------------- small k/v projection (fp32): kvp[(b*2+kv)*15+slot][1024] ----------------
__global__ __launch_bounds__(256) void proj_kv_small(
    const float* __restrict__ k, const float* __restrict__ v,
    const float* __restrict__ ipw, const float* __restrict__ ipb,
    float* __restrict__ kvp) {
    int fc  = blockIdx.x & 63;
    int bkv = blockIdx.x >> 6;
    int kv  = bkv & 1;
    int b   = bkv >> 1;

    const float* x0 = (kv ? v : k) + (size_t)b * SEQ * EMB;
    const float* Wm = ipw + (size_t)(1 + kv) * EMB * EMB;
    const float* bb = ipb + (size_t)(1 + kv) * EMB;

    __shared__ __align__(16) float xs[NSLOT][EMB];
    int tid = threadIdx.x;
#pragma unroll
    for (int i = 0; i < NSLOT; i++) {
        int pos = (i < 11) ? i : (SEQ - 4 + (i - 11));
        *(float4*)&xs[i][tid * 4] = *(const float4*)&x0[(size_t)pos * EMB + tid * 4];
    }
    __syncthreads();

    if (tid < 240) {
        int row  = tid >> 4;           // slot 0..14
        int feat = fc * 16 + (tid & 15);
        const float* wrow = Wm + (size_t)feat * EMB;
        float acc = 0.f;
        for (int kk = 0; kk < EMB; kk += 4) {
            float4 xv = *(const float4*)&xs[row][kk];
            float4 wv = *(const float4*)&wrow[kk];
            acc += xv.x * wv.x + xv.y * wv.y + xv.z * wv.z + xv.w * wv.w;
        }
        kvp[((size_t)((b * 2 + kv) * NSLOT + row)) * EMB + feat] = acc + bb[feat];
    }
}

// ---------------- merged precompute: G/cvec (gmat part) + UT (umat part) ----------------
// blocks [0, nGm): G[b][hs][e] = Wq_h^T kh_h[s], cvec[b][hs] = bq_h . kh_h[s]
// blocks [nGm, nGm+Bb*64): UT[b][e][hs] = vh_h[s] . Wo[e, hHD..]
union GUShared {
    struct { float xs[HD]; float red[HD]; } gm;
    float vs[NSLOT][EMB + 4];
};
__global__ __launch_bounds__(256) void gu_pre(
    const float* __restrict__ kvp, const float* __restrict__ ipw,
    const float* __restrict__ ipb, const float* __restrict__ outw,
    ushort_t* __restrict__ G, float* __restrict__ cvec,
    ushort_t* __restrict__ UT, int nGm) {
    __shared__ __align__(16) GUShared sm;
    int tid = threadIdx.x;

    if (blockIdx.x < (unsigned)nGm) {
        // ---- gmat ----
        int hs = blockIdx.x & 127, b = blockIdx.x >> 7;
        int h = hs >> 4, s = hs & 15;
        if (tid < HD)
            sm.gm.xs[tid] = (s < NSLOT)
                ? kvp[((size_t)((b * 2 + 0) * NSLOT + s)) * EMB + h * HD + tid] : 0.f;
        __syncthreads();
        int e0 = tid * 4;
        float a0 = 0.f, a1 = 0.f, a2 = 0.f, a3 = 0.f;
        for (int d = 0; d < HD; d++) {
            float xv = sm.gm.xs[d];
            const float* wr_ = ipw + (size_t)(h * HD + d) * EMB + e0;
            a0 += xv * wr_[0]; a1 += xv * wr_[1]; a2 += xv * wr_[2]; a3 += xv * wr_[3];
        }
        ushort4v gv; gv[0] = f2bf(a0); gv[1] = f2bf(a1); gv[2] = f2bf(a2); gv[3] = f2bf(a3);
        *(ushort4v*)&G[((size_t)b * 128 + hs) * EMB + e0] = gv;

        if (tid < HD) sm.gm.red[tid] = sm.gm.xs[tid] * ipb[h * HD + tid];
        __syncthreads();
        if (tid < 64) {
            float vsum = sm.gm.red[tid] + sm.gm.red[tid + 64];
            vsum += __shfl_down(vsum, 32, 64); vsum += __shfl_down(vsum, 16, 64);
            vsum += __shfl_down(vsum, 8, 64);  vsum += __shfl_down(vsum, 4, 64);
            vsum += __shfl_down(vsum, 2, 64);  vsum += __shfl_down(vsum, 1, 64);
            if (tid == 0) cvec[b * 128 + hs] = vsum;
        }
    } else {
        // ---- umat ----
        int idx = blockIdx.x - nGm;
        int ec = idx & 63, b = idx >> 6;
#pragma unroll
        for (int i = 0; i < NSLOT; i++)
            *(float4*)&sm.vs[i][tid * 4] =
                *(const float4*)&kvp[((size_t)((b * 2 + 1) * NSLOT + i)) * EMB + tid * 4];
        __syncthreads();
        int half = tid >> 7, hs = tid & 127, h = hs >> 4, s = hs & 15;
        for (int ei = 0; ei < 8; ei++) {
            int e = ec * 16 + half * 8 + ei;
            float acc = 0.f;
            if (s < NSLOT) {
                const float* orow = outw + (size_t)e * EMB + h * HD;
                const float* vrow = &sm.vs[s][h * HD];
                for (int d = 0; d < HD; d++) acc += vrow[d] * orow[d];
            }
            UT[((size_t)b * EMB + e) * 128 + hs] = f2bf(acc);
        }
    }
}

// ---------------- fused scores + softmax + output GEMM ----------------
// Block = 32 t-rows. Phase 1: S = q@G^T + c (A-frags direct from global via cvt_pk,
// no LDS/barriers). Softmax in slot space -> P in LDS (granule-XOR swizzled).
// Phase 2: out = P @ UT^T + outb (K=128, UT from L2).
#define TBM 32
__global__ __launch_bounds__(256) void score_out(
    const float* __restrict__ q, const ushort_t* __restrict__ G,
    const float* __restrict__ cvec, const ushort_t* __restrict__ UT,
    const float* __restrict__ outb, float* __restrict__ out) {
    __shared__ __align__(16) ushort_t pl[TBM * 128];   // 8 KB

    int tid = threadIdx.x, lane = tid & 63, w = tid >> 6;
    int fr = lane & 15, g = lane >> 4;
    int lb  = xcd_swz(blockIdx.x, gridDim.x);
    int mb0 = lb * TBM;
    int b   = mb0 >> 12;

    // ---- phase 1: S(32 x 32hs per wave) ----
    const ushort_t* Gb = G + (size_t)b * 128 * EMB;
    int hsb = w * 32;                    // wave w covers heads 2w, 2w+1
    f32x4 acc[2][2] = {};
#pragma unroll 4
    for (int kk = 0; kk < 32; kk++) {
        int k0 = kk * 32 + g * 8;
        bf16x8 af[2], bfb[2];
#pragma unroll
        for (int m = 0; m < 2; m++) {
            const float* qa = q + (size_t)(mb0 + m * 16 + fr) * EMB + k0;
            float4 x0 = *(const float4*)qa;
            float4 x1 = *(const float4*)(qa + 4);
            af[m] = cvt8(x0, x1);
        }
#pragma unroll
        for (int n = 0; n < 2; n++)
            bfb[n] = *(const bf16x8*)&Gb[(size_t)(hsb + n * 16 + fr) * EMB + k0];
#pragma unroll
        for (int m = 0; m < 2; m++)
#pragma unroll
            for (int n = 0; n < 2; n++)
                acc[m][n] = __builtin_amdgcn_mfma_f32_16x16x32_bf16(
                    af[m], bfb[n], acc[m][n], 0, 0, 0);
    }

    // ---- softmax (per (t, head) over 16 slots = 16 lanes) -> P in LDS ----
    float cv0 = cvec[b * 128 + hsb + fr];
    float cv1 = cvec[b * 128 + hsb + 16 + fr];
    const float scale = 0.08838834764831845f;   // 1/sqrt(128)
#pragma unroll
    for (int m = 0; m < 2; m++) {
#pragma unroll
        for (int r = 0; r < 4; r++) {
            int row = m * 16 + g * 4 + r;
            int tl  = (mb0 + row) & (SEQ - 1);
            int cse = (tl >= 4 && tl <= SEQ - 4) ? 7 : ((tl < 4) ? tl : tl - (SEQ - 3) + 4);
            float mult = (float)((MULT[cse] >> (fr * 2)) & 3u);
#pragma unroll
            for (int n = 0; n < 2; n++) {
                float vv = (acc[m][n][r] + (n ? cv1 : cv0)) * scale;
                float vm = (mult != 0.f) ? vv : -1e30f;
#pragma unroll
                for (int sh = 1; sh < 16; sh <<= 1) vm = fmaxf(vm, __shfl_xor(vm, sh, 64));
                float e_ = mult * expf(vv - vm);
                float z = e_;
#pragma unroll
                for (int sh = 1; sh < 16; sh <<= 1) z += __shfl_xor(z, sh, 64);
                int col = hsb + n * 16 + fr;
                int cg  = col >> 3;
                int pg  = (cg & 8) | ((cg & 7) ^ (row & 7));   // granule XOR swizzle
                pl[row * 128 + (pg << 3) + (col & 7)] = f2bf(e_ / z);
            }
        }
    }
    __syncthreads();

    // ---- phase 2: out(32 x 256e per wave) = P @ UT^T ----
    const ushort_t* UTb = UT + (size_t)b * EMB * 128;
    int eb = w * 256;
#pragma unroll 4
    for (int n = 0; n < 16; n++) {
        int e = eb + n * 16 + fr;
        f32x4 o2[2] = {};
#pragma unroll
        for (int kk = 0; kk < 4; kk++) {
            int gi = kk * 4 + g;
            bf16x8 ub = *(const bf16x8*)&UTb[(size_t)e * 128 + kk * 32 + g * 8];
#pragma unroll
            for (int m = 0; m < 2; m++) {
                int row = m * 16 + fr;
                int pg  = (gi & 8) | ((gi & 7) ^ (row & 7));
                bf16x8 pa = *(const bf16x8*)&pl[row * 128 + (pg << 3)];
                o2[m] = __builtin_amdgcn_mfma_f32_16x16x32_bf16(pa, ub, o2[m], 0, 0, 0);
            }
        }
        float bn = outb[e];
#pragma unroll
        for (int m = 0; m < 2; m++)
#pragma unroll
            for (int r = 0; r < 4; r++)
                out[(size_t)(mb0 + m * 16 + g * 4 + r) * EMB + e] = o2[m][r] + bn;
    }
}

// ---------------- launcher ----------------
extern "C" void kernel_launch(void* const* d_in, const int* in_sizes, int n_in,
                              void* d_out, int out_size, void* d_ws, size_t ws_size,
                              hipStream_t stream) {
    const float* q    = (const float*)d_in[0];
    const float* k    = (const float*)d_in[1];
    const float* v    = (const float*)d_in[2];
    const float* ipw  = (const float*)d_in[3];
    const float* ipb  = (const float*)d_in[4];
    const float* outw = (const float*)d_in[5];
    const float* outb = (const float*)d_in[6];
    float* out = (float*)d_out;

    int Bb = in_sizes[0] / (SEQ * EMB);     // batch (=2)
    int M  = Bb * SEQ;                      // 8192

    float*    kvp  = (float*)d_ws;                                     // Bb*2*15*1024 f32
    ushort_t* G    = (ushort_t*)(kvp + (size_t)Bb * 2 * NSLOT * EMB);  // Bb*128*1024 bf16
    ushort_t* UTm  = G + (size_t)Bb * 128 * EMB;                       // Bb*1024*128 bf16
    float*    cvec = (float*)(UTm + (size_t)Bb * EMB * 128);           // Bb*128 f32

    proj_kv_small<<<dim3(Bb * 2 * 64), dim3(256), 0, stream>>>(k, v, ipw, ipb, kvp);
    gu_pre<<<dim3(Bb * 128 + Bb * 64), dim3(256), 0, stream>>>(
        kvp, ipw, ipb, outw, G, cvec, UTm, Bb * 128);
    score_out<<<dim3(M / TBM), dim3(256), 0, stream>>>(q, G, cvec, UTm, outb, out);
}

// Round 10
// 89.559 us; speedup vs baseline: 1.0845x; 1.0845x over previous
//
#include <hip/hip_runtime.h>
#include <hip/hip_bf16.h>
#include <math.h>

// ---------------- problem constants ----------------
#define SEQ   4096
#define EMB   1024
#define NH    8
#define HD    128
#define NSLOT 15   // distinct gathered positions: 0..10, S-4..S-1 (+1 zero pad slot = 16)

typedef __attribute__((ext_vector_type(8))) short bf16x8;
typedef __attribute__((ext_vector_type(4))) float f32x4;
typedef __attribute__((ext_vector_type(4))) unsigned short ushort4v;
typedef unsigned short ushort_t;

// per-t slot multiplicity masks, 2 bits per slot (slot s at bits 2s..2s+1).
__device__ __constant__ unsigned int MULT[8] = {
    0x00005555u,  // t=0:   slots {0..7}
    0x10015055u,  // t=1:   {0,1,2,3,6,7,8,14}
    0x14050055u,  // t=2:   {0,1,2,3,8,9,13,14}
    0x15100055u,  // t=3:   {0,1,2,3,10,12,13,14}
    0x15800015u,  // t=S-3: {0,1,2, 11x2, 12,13,14}
    0x16800005u,  // t=S-2: {0,1, 11x2, 12x2, 13,14}
    0x1A800001u,  // t=S-1: {0, 11x2, 12x2, 13x2, 14}
    0x15400055u   // interior: {0,1,2,3,11,12,13,14}
};

__device__ __forceinline__ unsigned short f2bf(float x) {
    unsigned int u = __float_as_uint(x);
    return (unsigned short)((u + 0x7FFFu + ((u >> 16) & 1u)) >> 16);
}

// 8x fp32 -> bf16x8 via v_cvt_pk_bf16_f32 (RNE; no builtin on gfx950)
__device__ __forceinline__ bf16x8 cvt8(float4 a, float4 b) {
    union { unsigned int u[4]; bf16x8 v; } r;
    asm("v_cvt_pk_bf16_f32 %0, %1, %2" : "=v"(r.u[0]) : "v"(a.x), "v"(a.y));
    asm("v_cvt_pk_bf16_f32 %0, %1, %2" : "=v"(r.u[1]) : "v"(a.z), "v"(a.w));
    asm("v_cvt_pk_bf16_f32 %0, %1, %2" : "=v"(r.u[2]) : "v"(b.x), "v"(b.y));
    asm("v_cvt_pk_bf16_f32 %0, %1, %2" : "=v"(r.u[3]) : "v"(b.z), "v"(b.w));
    return r.v;
}

// async global->LDS, 16B per lane; lds ptr must be wave-uniform
__device__ __forceinline__ void gld16f(const float* g, float* l) {
    __builtin_amdgcn_global_load_lds(
        (const __attribute__((address_space(1))) unsigned int*)g,
        (__attribute__((address_space(3))) unsigned int*)l, 16, 0, 0);
}

// bijective chunked XCD swizzle (nwg % 8 == 0)
__device__ __forceinline__ int xcd_swz(int bid, int nwg) {
    int cpx = nwg >> 3;
    return (bid & 7) * cpx + (bid >> 3);
}

// ---------------- small k/v projection (fp32): kvp[(b*2+kv)*15+slot][1024] ----------------
__global__ __launch_bounds__(256) void proj_kv_small(
    const float* __restrict__ k, const float* __restrict__ v,
    const float* __restrict__ ipw, const float* __restrict__ ipb,
    float* __restrict__ kvp) {
    int fc  = blockIdx.x & 63;
    int bkv = blockIdx.x >> 6;
    int kv  = bkv & 1;
    int b   = bkv >> 1;

    const float* x0 = (kv ? v : k) + (size_t)b * SEQ * EMB;
    const float* Wm = ipw + (size_t)(1 + kv) * EMB * EMB;
    const float* bb = ipb + (size_t)(1 + kv) * EMB;

    __shared__ __align__(16) float xs[NSLOT][EMB];
    int tid = threadIdx.x;
#pragma unroll
    for (int i = 0; i < NSLOT; i++) {
        int pos = (i < 11) ? i : (SEQ - 4 + (i - 11));
        *(float4*)&xs[i][tid * 4] = *(const float4*)&x0[(size_t)pos * EMB + tid * 4];
    }
    __syncthreads();

    if (tid < 240) {
        int row  = tid >> 4;           // slot 0..14
        int feat = fc * 16 + (tid & 15);
        const float* wrow = Wm + (size_t)feat * EMB;
        float acc = 0.f;
        for (int kk = 0; kk < EMB; kk += 4) {
            float4 xv = *(const float4*)&xs[row][kk];
            float4 wv = *(const float4*)&wrow[kk];
            acc += xv.x * wv.x + xv.y * wv.y + xv.z * wv.z + xv.w * wv.w;
        }
        kvp[((size_t)((b * 2 + kv) * NSLOT + row)) * EMB + feat] = acc + bb[feat];
    }
}

// ---------------- merged precompute: G/cvec (gmat part) + UT (umat part) ----------------
union GUShared {
    struct { float xs[HD]; float red[HD]; } gm;
    float vs[NSLOT][EMB + 4];
};
__global__ __launch_bounds__(256) void gu_pre(
    const float* __restrict__ kvp, const float* __restrict__ ipw,
    const float* __restrict__ ipb, const float* __restrict__ outw,
    ushort_t* __restrict__ G, float* __restrict__ cvec,
    ushort_t* __restrict__ UT, int nGm) {
    __shared__ __align__(16) GUShared sm;
    int tid = threadIdx.x;

    if (blockIdx.x < (unsigned)nGm) {
        // ---- gmat: G[b][hs][e] = Wq_h^T kh_h[s]; cvec = bq_h . kh_h[s] ----
        int hs = blockIdx.x & 127, b = blockIdx.x >> 7;
        int h = hs >> 4, s = hs & 15;
        if (tid < HD)
            sm.gm.xs[tid] = (s < NSLOT)
                ? kvp[((size_t)((b * 2 + 0) * NSLOT + s)) * EMB + h * HD + tid] : 0.f;
        __syncthreads();
        int e0 = tid * 4;
        float a0 = 0.f, a1 = 0.f, a2 = 0.f, a3 = 0.f;
        for (int d = 0; d < HD; d++) {
            float xv = sm.gm.xs[d];
            const float* wr_ = ipw + (size_t)(h * HD + d) * EMB + e0;
            a0 += xv * wr_[0]; a1 += xv * wr_[1]; a2 += xv * wr_[2]; a3 += xv * wr_[3];
        }
        ushort4v gv; gv[0] = f2bf(a0); gv[1] = f2bf(a1); gv[2] = f2bf(a2); gv[3] = f2bf(a3);
        *(ushort4v*)&G[((size_t)b * 128 + hs) * EMB + e0] = gv;

        if (tid < HD) sm.gm.red[tid] = sm.gm.xs[tid] * ipb[h * HD + tid];
        __syncthreads();
        if (tid < 64) {
            float vsum = sm.gm.red[tid] + sm.gm.red[tid + 64];
            vsum += __shfl_down(vsum, 32, 64); vsum += __shfl_down(vsum, 16, 64);
            vsum += __shfl_down(vsum, 8, 64);  vsum += __shfl_down(vsum, 4, 64);
            vsum += __shfl_down(vsum, 2, 64);  vsum += __shfl_down(vsum, 1, 64);
            if (tid == 0) cvec[b * 128 + hs] = vsum;
        }
    } else {
        // ---- umat: UT[b][e][hs] = vh_h[s] . Wo[e, hHD..] ----
        int idx = blockIdx.x - nGm;
        int ec = idx & 63, b = idx >> 6;
#pragma unroll
        for (int i = 0; i < NSLOT; i++)
            *(float4*)&sm.vs[i][tid * 4] =
                *(const float4*)&kvp[((size_t)((b * 2 + 1) * NSLOT + i)) * EMB + tid * 4];
        __syncthreads();
        int half = tid >> 7, hs = tid & 127, h = hs >> 4, s = hs & 15;
        for (int ei = 0; ei < 8; ei++) {
            int e = ec * 16 + half * 8 + ei;
            float acc = 0.f;
            if (s < NSLOT) {
                const float* orow = outw + (size_t)e * EMB + h * HD;
                const float* vrow = &sm.vs[s][h * HD];
                for (int d = 0; d < HD; d++) acc += vrow[d] * orow[d];
            }
            UT[((size_t)b * EMB + e) * 128 + hs] = f2bf(acc);
        }
    }
}

// ---------------- fused scores + softmax + output GEMM ----------------
// Block = 16 t-rows, 256 threads, grid 512 (2 blocks/CU). Phase 1: q async-staged
// via global_load_lds (3 buffers, depth-2, counted vmcnt), G reg-prefetched depth-1,
// S = q@G^T + c. Softmax in slot space -> P in LDS. Phase 2: out = P @ UT^T + outb.
#define TBM 16
#define NTQ 16
__global__ __launch_bounds__(256) void score_out(
    const float* __restrict__ q, const ushort_t* __restrict__ G,
    const float* __restrict__ cvec, const ushort_t* __restrict__ UT,
    const float* __restrict__ outb, float* __restrict__ out) {
    __shared__ __align__(16) union {
        float st[3][TBM * 64];          // 12 KB q staging (16 rows x 64 fp32, swizzled)
        ushort_t pl[TBM * 128];         // 4 KB P
    } sm;

    int tid = threadIdx.x, lane = tid & 63, w = tid >> 6;
    int fr = lane & 15, g = lane >> 4;
    int lb  = xcd_swz(blockIdx.x, gridDim.x);
    int mb0 = lb * TBM;
    int b   = mb0 >> 12;

    // staging: physical slot (row=tid>>4, pgc=tid&15); logical granule = inv-swizzle
    int srow = tid >> 4, pgc = tid & 15;
    int gidx = (pgc & 8) | ((pgc & 7) ^ (srow & 7));
    const float* qsrc = q + (size_t)(mb0 + srow) * EMB + gidx * 4;

    const ushort_t* Gb  = G + (size_t)b * 128 * EMB;
    int hsb = w * 32;                    // wave w covers heads 2w, 2w+1
    const ushort_t* g0p = &Gb[(size_t)(hsb + fr) * EMB + g * 8];
    const ushort_t* g1p = &Gb[(size_t)(hsb + 16 + fr) * EMB + g * 8];
    float cv0 = cvec[b * 128 + hsb + fr];
    float cv1 = cvec[b * 128 + hsb + 16 + fr];

    f32x4 acc[2] = {};
    bf16x8 Gp[4], Gq[4];                 // [sub*2+n] ping/pong G fragments

#define STAGEQ(t_) gld16f(qsrc + (t_) * 64, &sm.st[(t_) % 3][w * 256])
#define LOADG(dst_, t_) do {                                   \
        dst_[0] = *(const bf16x8*)&g0p[(t_) * 64];             \
        dst_[1] = *(const bf16x8*)&g1p[(t_) * 64];             \
        dst_[2] = *(const bf16x8*)&g0p[(t_) * 64 + 32];        \
        dst_[3] = *(const bf16x8*)&g1p[(t_) * 64 + 32];        \
    } while (0)
#define COMP(Gr_, t_) do {                                                     \
        const float* stc = sm.st[(t_) % 3];                                    \
        __builtin_amdgcn_s_setprio(1);                                         \
        _Pragma("unroll")                                                      \
        for (int sub = 0; sub < 2; sub++) {                                    \
            int p0 = sub * 8 + ((2 * g) ^ (fr & 7));                           \
            int p1 = sub * 8 + ((2 * g + 1) ^ (fr & 7));                       \
            float4 x0 = *(const float4*)&stc[fr * 64 + p0 * 4];                \
            float4 x1 = *(const float4*)&stc[fr * 64 + p1 * 4];                \
            bf16x8 af = cvt8(x0, x1);                                          \
            acc[0] = __builtin_amdgcn_mfma_f32_16x16x32_bf16(                  \
                af, Gr_[sub * 2 + 0], acc[0], 0, 0, 0);                        \
            acc[1] = __builtin_amdgcn_mfma_f32_16x16x32_bf16(                  \
                af, Gr_[sub * 2 + 1], acc[1], 0, 0, 0);                        \
        }                                                                      \
        __builtin_amdgcn_s_setprio(0);                                         \
    } while (0)
#define ITER(t_, Gcur_, Gnxt_) do {                                            \
        if ((t_) + 1 < NTQ) LOADG(Gnxt_, (t_) + 1);                            \
        if ((t_) + 2 < NTQ) STAGEQ((t_) + 2);                                  \
        COMP(Gcur_, t_);                                                       \
        if ((t_) + 2 < NTQ)                                                    \
            asm volatile("s_waitcnt vmcnt(5)" ::: "memory");                   \
        else if ((t_) + 1 < NTQ)                                               \
            asm volatile("s_waitcnt vmcnt(4)" ::: "memory");                   \
        if ((t_) + 1 < NTQ) __builtin_amdgcn_s_barrier();                      \
    } while (0)

    // prologue: 2 q-tiles in flight + G tile 0 in regs
    STAGEQ(0); STAGEQ(1);
    LOADG(Gp, 0);
    asm volatile("s_waitcnt vmcnt(5)" ::: "memory");   // q tile 0 landed
    __builtin_amdgcn_s_barrier();

#pragma unroll
    for (int tp = 0; tp < 8; tp++) {
        ITER(2 * tp, Gp, Gq);
        ITER(2 * tp + 1, Gq, Gp);
    }
#undef ITER
#undef COMP
#undef LOADG
#undef STAGEQ

    __syncthreads();   // all st reads done before pl-union overwrite

    // ---- softmax (per (t, head) over 16 slots = 16 lanes) -> P in LDS ----
    const float scale = 0.08838834764831845f;   // 1/sqrt(128)
#pragma unroll
    for (int r = 0; r < 4; r++) {
        int row = g * 4 + r;
        int tl  = (mb0 + row) & (SEQ - 1);
        int cse = (tl >= 4 && tl <= SEQ - 4) ? 7 : ((tl < 4) ? tl : tl - (SEQ - 3) + 4);
        float mult = (float)((MULT[cse] >> (fr * 2)) & 3u);
#pragma unroll
        for (int n = 0; n < 2; n++) {
            float vv = (acc[n][r] + (n ? cv1 : cv0)) * scale;
            float vm = (mult != 0.f) ? vv : -1e30f;
#pragma unroll
            for (int sh = 1; sh < 16; sh <<= 1) vm = fmaxf(vm, __shfl_xor(vm, sh, 64));
            float e_ = mult * expf(vv - vm);
            float z = e_;
#pragma unroll
            for (int sh = 1; sh < 16; sh <<= 1) z += __shfl_xor(z, sh, 64);
            int col = hsb + n * 16 + fr;
            int cg  = col >> 3;
            int pg  = (cg & 8) | ((cg & 7) ^ (row & 7));   // granule XOR swizzle
            sm.pl[row * 128 + pg * 8 + (col & 7)] = f2bf(e_ / z);
        }
    }
    __syncthreads();

    // ---- phase 2: out(16 x 256e per wave) = P @ UT^T + outb ----
    const ushort_t* UTb = UT + (size_t)b * EMB * 128;
    int eb = w * 256;
#pragma unroll 4
    for (int n = 0; n < 16; n++) {
        int e = eb + n * 16 + fr;
        f32x4 o2 = {};
#pragma unroll
        for (int kk = 0; kk < 4; kk++) {
            int gi = kk * 4 + g;
            bf16x8 ub = *(const bf16x8*)&UTb[(size_t)e * 128 + kk * 32 + g * 8];
            int pg = (gi & 8) | ((gi & 7) ^ (fr & 7));
            bf16x8 pa = *(const bf16x8*)&sm.pl[fr * 128 + pg * 8];
            o2 = __builtin_amdgcn_mfma_f32_16x16x32_bf16(pa, ub, o2, 0, 0, 0);
        }
        float bn = outb[e];
#pragma unroll
        for (int r = 0; r < 4; r++)
            out[(size_t)(mb0 + g * 4 + r) * EMB + e] = o2[r] + bn;
    }
}

// ---------------- launcher ----------------
extern "C" void kernel_launch(void* const* d_in, const int* in_sizes, int n_in,
                              void* d_out, int out_size, void* d_ws, size_t ws_size,
                              hipStream_t stream) {
    const float* q    = (const float*)d_in[0];
    const float* k    = (const float*)d_in[1];
    const float* v    = (const float*)d_in[2];
    const float* ipw  = (const float*)d_in[3];
    const float* ipb  = (const float*)d_in[4];
    const float* outw = (const float*)d_in[5];
    const float* outb = (const float*)d_in[6];
    float* out = (float*)d_out;

    int Bb = in_sizes[0] / (SEQ * EMB);     // batch (=2)
    int M  = Bb * SEQ;                      // 8192

    float*    kvp  = (float*)d_ws;                                     // Bb*2*15*1024 f32
    ushort_t* G    = (ushort_t*)(kvp + (size_t)Bb * 2 * NSLOT * EMB);  // Bb*128*1024 bf16
    ushort_t* UTm  = G + (size_t)Bb * 128 * EMB;                       // Bb*1024*128 bf16
    float*    cvec = (float*)(UTm + (size_t)Bb * EMB * 128);           // Bb*128 f32

    proj_kv_small<<<dim3(Bb * 2 * 64), dim3(256), 0, stream>>>(k, v, ipw, ipb, kvp);
    gu_pre<<<dim3(Bb * 128 + Bb * 64), dim3(256), 0, stream>>>(
        kvp, ipw, ipb, outw, G, cvec, UTm, Bb * 128);
    score_out<<<dim3(M / TBM), dim3(256), 0, stream>>>(q, G, cvec, UTm, outb, out);
}